// Round 6
// baseline (108302.161 us; speedup 1.0000x reference)
//
#include <hip/hip_runtime.h>

#define DI __device__ __forceinline__

// Problem constants
constexpr int Bsz = 1024;   // batch
constexpr int Hh  = 512;    // hidden
constexpr int Tt  = 128;    // seq len
constexpr int G3  = 1536;   // 3H
constexpr int STEPS = 2 * Tt - 1;  // 128 TF + 127 AR = 255 sequential GRU steps

// Persistent-kernel config
constexpr int NBLK = 512;   // 2 blocks/CU on 256 CUs (resource-guaranteed co-resident)
constexpr int NTHR = 256;
constexpr int BM = 64, BN = 96, BK = 64;   // 16 m-tiles x 16 n-tiles = 256 tiles

struct GBar { unsigned cnt; unsigned gen; };

struct Args {
  const float* x;
  const float* w_ih0; const float* w_hh0; const float* b_ih0; const float* b_hh0;
  const float* w_ih1; const float* w_hh1; const float* b_ih1; const float* b_hh1;
  const float* w_lin; const float* b_lin;
  float* out;
  GBar* bar;
  float* h0a; float* h0b; float* h1;
  float* ghp0; float* ghp1;   // split-K halves of gh0 [B,3H]
  float* gi1;  float* gh1;    // layer-1 gate pre-activations [B,3H]
  float* pred;                // [B] fed back in AR phase
};

// Sense-reversing grid barrier. Device(agent)-scope atomics: the release RMW
// on arrival publishes this block's prior global stores (cross-XCD, via L2
// writeback the backend emits for agent-scope release); the acquire spin on
// `gen` pulls them in. Same primitive cg::grid_group::sync uses internally,
// minus the cooperative-launch co-residency gatekeeping that silently
// rejected our launch (round1/round3: d_out stayed memset-zero, error was
// exactly max|ref| = 50x the 2%-relative threshold, bit-identical across
// different kernels).
DI void grid_barrier(GBar* b) {
  __syncthreads();
  if (threadIdx.x == 0) {
    unsigned g = __hip_atomic_load(&b->gen, __ATOMIC_RELAXED, __HIP_MEMORY_SCOPE_AGENT);
    unsigned old = __hip_atomic_fetch_add(&b->cnt, 1u, __ATOMIC_ACQ_REL, __HIP_MEMORY_SCOPE_AGENT);
    if (old == (unsigned)NBLK - 1u) {
      __hip_atomic_store(&b->cnt, 0u, __ATOMIC_RELAXED, __HIP_MEMORY_SCOPE_AGENT);
      __hip_atomic_fetch_add(&b->gen, 1u, __ATOMIC_RELEASE, __HIP_MEMORY_SCOPE_AGENT);
    } else {
      while (__hip_atomic_load(&b->gen, __ATOMIC_ACQUIRE, __HIP_MEMORY_SCOPE_AGENT) == g)
        __builtin_amdgcn_s_sleep(1);
    }
  }
  __syncthreads();
}

DI float4 ld4(const float* p) { return *reinterpret_cast<const float4*>(p); }
DI void   st4(float* p, float4 v) { *reinterpret_cast<float4*>(p) = v; }

// Precise transcendentals (libm ~1ulp); AR feedback amplifies gate error.
DI float sigmf_(float a) { return 1.0f / (1.0f + expf(-a)); }

// PyTorch GRU cell elementwise, gate order (r,z,n)
DI float gru_h(float gi_r, float gi_z, float gi_n,
               float gh_r, float gh_z, float gh_n, float h) {
  float r = sigmf_(gi_r + gh_r);
  float z = sigmf_(gi_z + gh_z);
  float n = tanhf(gi_n + r * gh_n);
  return (1.0f - z) * n + z * h;
}

// C[m0+0..63][n0+0..95] = sum_{k0<=k<k1} A[m][k]*W[n][k]  (+bias[n])
// A: row-major [*, 512]; W: row-major [1536, 512]; C: row-major [*, 1536]
// LDS: float4 tiles, XOR-swizzled in f4-units: physical col = c ^ ((row>>2)&15)
//  -> staging writes 2-way aliased (free per m136), fragment reads <=2-way.
DI void gemm64x96(const float* __restrict__ Ag, const float* __restrict__ Wg,
                  float* __restrict__ Cg, const float* __restrict__ bias,
                  int m0, int n0, int k0, int k1, int tid,
                  float4 (*As)[16], float4 (*Ws)[16])
{
  const int ty = tid >> 4;   // 0..15 -> 4 output rows each
  const int tx = tid & 15;   // 0..15 -> 6 output cols each
  float acc[4][6];
#pragma unroll
  for (int i = 0; i < 4; ++i)
#pragma unroll
    for (int j = 0; j < 6; ++j) acc[i][j] = 0.f;

  int nsw[6];
#pragma unroll
  for (int j = 0; j < 6; ++j) nsw[j] = ((6 * tx + j) >> 2) & 15;

  for (int kc = k0; kc < k1; kc += BK) {
    // stage A chunk: 64 rows x 16 f4
#pragma unroll
    for (int r = 0; r < 4; ++r) {
      int idx = tid + NTHR * r;
      int m = idx >> 4, c = idx & 15;
      As[m][c ^ ((m >> 2) & 15)] = ld4(Ag + (size_t)(m0 + m) * Hh + kc + 4 * c);
    }
    // stage W chunk: 96 rows x 16 f4
#pragma unroll
    for (int r = 0; r < 6; ++r) {
      int idx = tid + NTHR * r;
      int n = idx >> 4, c = idx & 15;
      Ws[n][c ^ ((n >> 2) & 15)] = ld4(Wg + (size_t)(n0 + n) * Hh + kc + 4 * c);
    }
    __syncthreads();
#pragma unroll 4
    for (int k4 = 0; k4 < 16; ++k4) {
      float4 a4[4], w4[6];
#pragma unroll
      for (int i = 0; i < 4; ++i) a4[i] = As[4 * ty + i][k4 ^ ty]; // ((4ty+i)>>2)&15 == ty
#pragma unroll
      for (int j = 0; j < 6; ++j) w4[j] = Ws[6 * tx + j][k4 ^ nsw[j]];
#pragma unroll
      for (int i = 0; i < 4; ++i)
#pragma unroll
        for (int j = 0; j < 6; ++j) {
          acc[i][j] = fmaf(a4[i].x, w4[j].x, acc[i][j]);
          acc[i][j] = fmaf(a4[i].y, w4[j].y, acc[i][j]);
          acc[i][j] = fmaf(a4[i].z, w4[j].z, acc[i][j]);
          acc[i][j] = fmaf(a4[i].w, w4[j].w, acc[i][j]);
        }
    }
    __syncthreads();
  }
#pragma unroll
  for (int i = 0; i < 4; ++i) {
    size_t row = (size_t)(m0 + 4 * ty + i) * G3;
#pragma unroll
    for (int j = 0; j < 6; ++j) {
      int n = n0 + 6 * tx + j;
      float v = acc[i][j];
      if (bias) v += bias[n];
      Cg[row + n] = v;
    }
  }
}

// layer-1 elementwise + prediction for step tp; each block owns 2 batch rows.
DI void ew_h1(const Args& a, int tp, int bid, int tid, double* red)
{
  const int half = tid >> 7;              // 0/1 -> which of the 2 rows
  const int r = 2 * bid + half;
  const int j0 = (tid & 127) * 4;
  const size_t rg = (size_t)r * G3;
  float4 gir = ld4(a.gi1 + rg + j0);
  float4 ghr = ld4(a.gh1 + rg + j0);
  float4 giz = ld4(a.gi1 + rg + 512 + j0);
  float4 ghz = ld4(a.gh1 + rg + 512 + j0);
  float4 gin = ld4(a.gi1 + rg + 1024 + j0);
  float4 ghn = ld4(a.gh1 + rg + 1024 + j0);
  float4 hold = ld4(a.h1 + (size_t)r * Hh + j0);
  float4 wl = ld4(a.w_lin + j0);
  float4 hn;
  // fp64 accumulation for the fed-back prediction scalar (error compounds
  // through 127 AR steps; cost negligible at 1024 rows).
  double pd = 0.0;
#define COMP(C) { hn.C = gru_h(gir.C, giz.C, gin.C, ghr.C, ghz.C, ghn.C, hold.C); \
                  pd += (double)hn.C * (double)wl.C; }
  COMP(x) COMP(y) COMP(z) COMP(w)
#undef COMP
  st4(a.h1 + (size_t)r * Hh + j0, hn);
  // reduce 128 threads (2 waves) per row
#pragma unroll
  for (int s = 32; s; s >>= 1) pd += __shfl_down(pd, s);
  if ((tid & 63) == 0) red[tid >> 6] = pd;
  __syncthreads();
  if ((tid & 127) == 0) {
    int w0 = half * 2;
    float p0 = (float)(red[w0] + red[w0 + 1] + (double)a.b_lin[0]);
    a.pred[r] = p0;
    if (tp >= Tt - 1) a.out[(size_t)r * Tt + (tp - (Tt - 1))] = p0;
  }
}

__global__ __launch_bounds__(NTHR, 2) void regru_kernel(Args a)
{
  const int bid = blockIdx.x;
  const int tid = threadIdx.x;

  __shared__ float4 As[BM][16];
  __shared__ float4 Ws[BN][16];
  __shared__ double red[4];

  // init: zero h0 (buffer A) and h1 (ws is poisoned before every call)
  {
    size_t fi = (size_t)bid * NTHR + tid;    // 131072 threads == B*H/4 f4 elems
    float4 z4 = make_float4(0.f, 0.f, 0.f, 0.f);
    st4(a.h0a + fi * 4, z4);
    st4(a.h1 + fi * 4, z4);
  }
  grid_barrier(a.bar);

  for (int t = 0; t < STEPS; ++t) {
    float* h0cur = (t & 1) ? a.h0b : a.h0a;
    float* h0nxt = (t & 1) ? a.h0a : a.h0b;

    // ---- PH_A: finish step t-1 (h1 + pred) and gh0 GEMM (split-K, 2 halves) ----
    if (t > 0) ew_h1(a, t - 1, bid, tid, red);
    {
      int tile = bid >> 1, p = bid & 1;
      int m0 = (tile >> 4) * BM, n0 = (tile & 15) * BN;
      gemm64x96(h0cur, a.w_hh0, p ? a.ghp1 : a.ghp0,
                p == 0 ? a.b_hh0 : nullptr,   // fold b_hh0 into half 0
                m0, n0, p * 256, p * 256 + 256, tid, As, Ws);
    }
    grid_barrier(a.bar);

    // ---- PH_B: layer-0 GRU elementwise -> h0nxt (1 f4 per thread) ----
    {
      size_t fi = (size_t)bid * NTHR + tid;
      int b = (int)(fi >> 7);
      int j0 = (int)(fi & 127) * 4;
      float xv = (t < Tt) ? a.x[(size_t)b * Tt + t] : a.pred[b];
      size_t bg = (size_t)b * G3;
      float4 g0r = ld4(a.ghp0 + bg + j0),        g1r = ld4(a.ghp1 + bg + j0);
      float4 g0z = ld4(a.ghp0 + bg + 512 + j0),  g1z = ld4(a.ghp1 + bg + 512 + j0);
      float4 g0n = ld4(a.ghp0 + bg + 1024 + j0), g1n = ld4(a.ghp1 + bg + 1024 + j0);
      float4 wr = ld4(a.w_ih0 + j0),        br = ld4(a.b_ih0 + j0);
      float4 wz = ld4(a.w_ih0 + 512 + j0),  bz = ld4(a.b_ih0 + 512 + j0);
      float4 wn = ld4(a.w_ih0 + 1024 + j0), bn = ld4(a.b_ih0 + 1024 + j0);
      float4 hold = ld4(h0cur + (size_t)b * Hh + j0);
      float4 hn;
#define COMP(C) hn.C = gru_h(fmaf(xv, wr.C, br.C), fmaf(xv, wz.C, bz.C), \
                             fmaf(xv, wn.C, bn.C), g0r.C + g1r.C,        \
                             g0z.C + g1z.C, g0n.C + g1n.C, hold.C);
      COMP(x) COMP(y) COMP(z) COMP(w)
#undef COMP
      st4(h0nxt + (size_t)b * Hh + j0, hn);
    }
    grid_barrier(a.bar);

    // ---- PH_C: gi1 = h0n @ w_ih1^T, gh1 = h1 @ w_hh1^T (512 tiles / 512 blocks) ----
    {
      int g = bid >> 8, r = bid & 255;
      int m0 = (r >> 4) * BM, n0 = (r & 15) * BN;
      if (g == 0)
        gemm64x96(h0nxt, a.w_ih1, a.gi1, a.b_ih1, m0, n0, 0, Hh, tid, As, Ws);
      else
        gemm64x96(a.h1, a.w_hh1, a.gh1, a.b_hh1, m0, n0, 0, Hh, tid, As, Ws);
    }
    grid_barrier(a.bar);
  }
  // tail: finish step 254 -> out column 127
  ew_h1(a, STEPS - 1, bid, tid, red);
}

extern "C" void kernel_launch(void* const* d_in, const int* in_sizes, int n_in,
                              void* d_out, int out_size, void* d_ws, size_t ws_size,
                              hipStream_t stream)
{
  Args a;
  a.x     = (const float*)d_in[0];
  // d_in[1] (x_time) and d_in[2] (y_time) are unused by the reference computation
  a.w_ih0 = (const float*)d_in[3];
  a.w_hh0 = (const float*)d_in[4];
  a.b_ih0 = (const float*)d_in[5];
  a.b_hh0 = (const float*)d_in[6];
  a.w_ih1 = (const float*)d_in[7];
  a.w_hh1 = (const float*)d_in[8];
  a.b_ih1 = (const float*)d_in[9];
  a.b_hh1 = (const float*)d_in[10];
  a.w_lin = (const float*)d_in[11];
  a.b_lin = (const float*)d_in[12];
  a.out   = (float*)d_out;

  // barrier state at head of workspace (d_ws is poisoned 0xAA before every
  // call -> must re-zero; hipMemsetAsync is graph-capturable)
  a.bar = (GBar*)d_ws;
  hipMemsetAsync(d_ws, 0, 256, stream);

  float* w = (float*)((char*)d_ws + 256);
  size_t off = 0;
  auto take = [&](size_t n) { float* p = w + off; off += n; return p; };
  a.h0a  = take((size_t)Bsz * Hh);
  a.h0b  = take((size_t)Bsz * Hh);
  a.h1   = take((size_t)Bsz * Hh);
  a.ghp0 = take((size_t)Bsz * G3);
  a.ghp1 = take((size_t)Bsz * G3);
  a.gi1  = take((size_t)Bsz * G3);
  a.gh1  = take((size_t)Bsz * G3);
  a.pred = take((size_t)Bsz);
  // total ~31.5 MB of workspace

  regru_kernel<<<dim3(NBLK), dim3(NTHR), 0, stream>>>(a);
}

// Round 9
// 45667.923 us; speedup vs baseline: 2.3715x; 2.3715x over previous
//
#include <hip/hip_runtime.h>

#define DI __device__ __forceinline__

// Problem constants
constexpr int Bsz = 1024;   // batch
constexpr int Hh  = 512;    // hidden
constexpr int Tt  = 128;    // seq len
constexpr int G3  = 1536;   // 3H
constexpr int STEPS = 2 * Tt - 1;  // 128 TF + 127 AR = 255 sequential GRU steps

// Persistent-kernel config
constexpr int NBLK = 512;   // 2 blocks/CU on 256 CUs (resource-guaranteed co-resident)
constexpr int NTHR = 256;
constexpr int BM = 64, BN = 96, BK = 64;   // 16 m-tiles x 16 n-tiles = 256 tiles

struct Args {
  const float* x;
  const float* w_ih0; const float* w_hh0; const float* b_ih0; const float* b_hh0;
  const float* w_ih1; const float* w_hh1; const float* b_ih1; const float* b_hh1;
  const float* w_lin; const float* b_lin;
  float* out;
  unsigned* flags;            // [NBLK] per-block phase flags (distributed barrier)
  float* h0a; float* h0b; float* h1;
  float* ghp0; float* ghp1;   // split-K halves of gh0 [B,3H]
  float* gi1;  float* gh1;    // layer-1 gate pre-activations [B,3H]
  float* pred;                // [B] fed back in AR phase
};

// Distributed flag barrier (round-7 change).
// Round 6 measured ~155us/barrier with a central fetch_add: 512 serialized
// agent-scope RMWs to ONE cacheline + acquire-spin emitting buffer_inv per
// poll (L2 thrash). Here: arrival = release-store to the block's OWN flag
// word (512 distinct lines, parallel); wait = one wave polls all flags with
// RELAXED loads (no buffer_inv per iteration), then a single acquire fence
// publishes remote writes to this block. Phase values are monotonic
// (1..766), so no reset race; flags are re-zeroed by hipMemsetAsync each
// launch (graph-capturable).
DI void grid_barrier(unsigned* flags, unsigned phase) {
  __syncthreads();
  if (threadIdx.x == 0) {
    // release: publishes this block's prior global stores (emits L2 wb)
    __hip_atomic_store(&flags[blockIdx.x], phase, __ATOMIC_RELEASE,
                       __HIP_MEMORY_SCOPE_AGENT);
  }
  if (threadIdx.x < 64) {
    // one wave polls; lanes each own NBLK/64 = 8 flags
#pragma unroll
    for (int k = 0; k < NBLK / 64; ++k) {
      const unsigned idx = threadIdx.x + 64u * k;
      while (__hip_atomic_load(&flags[idx], __ATOMIC_RELAXED,
                               __HIP_MEMORY_SCOPE_AGENT) < phase)
        __builtin_amdgcn_s_sleep(2);
    }
    // one acquire fence for the whole poll (instead of per-load buffer_inv)
    __builtin_amdgcn_fence(__ATOMIC_ACQUIRE, "agent");
  }
  __syncthreads();
}

DI float4 ld4(const float* p) { return *reinterpret_cast<const float4*>(p); }
DI void   st4(float* p, float4 v) { *reinterpret_cast<float4*>(p) = v; }

// Precise transcendentals (libm ~1ulp); AR feedback amplifies gate error.
DI float sigmf_(float a) { return 1.0f / (1.0f + expf(-a)); }

// PyTorch GRU cell elementwise, gate order (r,z,n)
DI float gru_h(float gi_r, float gi_z, float gi_n,
               float gh_r, float gh_z, float gh_n, float h) {
  float r = sigmf_(gi_r + gh_r);
  float z = sigmf_(gi_z + gh_z);
  float n = tanhf(gi_n + r * gh_n);
  return (1.0f - z) * n + z * h;
}

// C[m0+0..63][n0+0..95] = sum_{k0<=k<k1} A[m][k]*W[n][k]  (+bias[n])
// A: row-major [*, 512]; W: row-major [1536, 512]; C: row-major [*, 1536]
// LDS: float4 tiles, XOR-swizzled in f4-units: physical col = c ^ ((row>>2)&15)
DI void gemm64x96(const float* __restrict__ Ag, const float* __restrict__ Wg,
                  float* __restrict__ Cg, const float* __restrict__ bias,
                  int m0, int n0, int k0, int k1, int tid,
                  float4 (*As)[16], float4 (*Ws)[16])
{
  const int ty = tid >> 4;   // 0..15 -> 4 output rows each
  const int tx = tid & 15;   // 0..15 -> 6 output cols each
  float acc[4][6];
#pragma unroll
  for (int i = 0; i < 4; ++i)
#pragma unroll
    for (int j = 0; j < 6; ++j) acc[i][j] = 0.f;

  int nsw[6];
#pragma unroll
  for (int j = 0; j < 6; ++j) nsw[j] = ((6 * tx + j) >> 2) & 15;

  for (int kc = k0; kc < k1; kc += BK) {
    // stage A chunk: 64 rows x 16 f4
#pragma unroll
    for (int r = 0; r < 4; ++r) {
      int idx = tid + NTHR * r;
      int m = idx >> 4, c = idx & 15;
      As[m][c ^ ((m >> 2) & 15)] = ld4(Ag + (size_t)(m0 + m) * Hh + kc + 4 * c);
    }
    // stage W chunk: 96 rows x 16 f4
#pragma unroll
    for (int r = 0; r < 6; ++r) {
      int idx = tid + NTHR * r;
      int n = idx >> 4, c = idx & 15;
      Ws[n][c ^ ((n >> 2) & 15)] = ld4(Wg + (size_t)(n0 + n) * Hh + kc + 4 * c);
    }
    __syncthreads();
#pragma unroll 4
    for (int k4 = 0; k4 < 16; ++k4) {
      float4 a4[4], w4[6];
#pragma unroll
      for (int i = 0; i < 4; ++i) a4[i] = As[4 * ty + i][k4 ^ ty]; // ((4ty+i)>>2)&15 == ty
#pragma unroll
      for (int j = 0; j < 6; ++j) w4[j] = Ws[6 * tx + j][k4 ^ nsw[j]];
#pragma unroll
      for (int i = 0; i < 4; ++i)
#pragma unroll
        for (int j = 0; j < 6; ++j) {
          acc[i][j] = fmaf(a4[i].x, w4[j].x, acc[i][j]);
          acc[i][j] = fmaf(a4[i].y, w4[j].y, acc[i][j]);
          acc[i][j] = fmaf(a4[i].z, w4[j].z, acc[i][j]);
          acc[i][j] = fmaf(a4[i].w, w4[j].w, acc[i][j]);
        }
    }
    __syncthreads();
  }
#pragma unroll
  for (int i = 0; i < 4; ++i) {
    size_t row = (size_t)(m0 + 4 * ty + i) * G3;
#pragma unroll
    for (int j = 0; j < 6; ++j) {
      int n = n0 + 6 * tx + j;
      float v = acc[i][j];
      if (bias) v += bias[n];
      Cg[row + n] = v;
    }
  }
}

// layer-1 elementwise + prediction for step tp; each block owns 2 batch rows.
DI void ew_h1(const Args& a, int tp, int bid, int tid, double* red)
{
  const int half = tid >> 7;              // 0/1 -> which of the 2 rows
  const int r = 2 * bid + half;
  const int j0 = (tid & 127) * 4;
  const size_t rg = (size_t)r * G3;
  float4 gir = ld4(a.gi1 + rg + j0);
  float4 ghr = ld4(a.gh1 + rg + j0);
  float4 giz = ld4(a.gi1 + rg + 512 + j0);
  float4 ghz = ld4(a.gh1 + rg + 512 + j0);
  float4 gin = ld4(a.gi1 + rg + 1024 + j0);
  float4 ghn = ld4(a.gh1 + rg + 1024 + j0);
  float4 hold = ld4(a.h1 + (size_t)r * Hh + j0);
  float4 wl = ld4(a.w_lin + j0);
  float4 hn;
  // fp64 accumulation for the fed-back prediction scalar (error compounds
  // through 127 AR steps; cost negligible at 1024 rows).
  double pd = 0.0;
#define COMP(C) { hn.C = gru_h(gir.C, giz.C, gin.C, ghr.C, ghz.C, ghn.C, hold.C); \
                  pd += (double)hn.C * (double)wl.C; }
  COMP(x) COMP(y) COMP(z) COMP(w)
#undef COMP
  st4(a.h1 + (size_t)r * Hh + j0, hn);
  // reduce 128 threads (2 waves) per row
#pragma unroll
  for (int s = 32; s; s >>= 1) pd += __shfl_down(pd, s);
  if ((tid & 63) == 0) red[tid >> 6] = pd;
  __syncthreads();
  if ((tid & 127) == 0) {
    int w0 = half * 2;
    float p0 = (float)(red[w0] + red[w0 + 1] + (double)a.b_lin[0]);
    a.pred[r] = p0;
    if (tp >= Tt - 1) a.out[(size_t)r * Tt + (tp - (Tt - 1))] = p0;
  }
}

__global__ __launch_bounds__(NTHR, 2) void regru_kernel(Args a)
{
  const int bid = blockIdx.x;
  const int tid = threadIdx.x;

  __shared__ float4 As[BM][16];
  __shared__ float4 Ws[BN][16];
  __shared__ double red[4];

  unsigned phase = 0;

  // init: zero h0 (buffer A) and h1 (ws is poisoned before every call)
  {
    size_t fi = (size_t)bid * NTHR + tid;    // 131072 threads == B*H/4 f4 elems
    float4 z4 = make_float4(0.f, 0.f, 0.f, 0.f);
    st4(a.h0a + fi * 4, z4);
    st4(a.h1 + fi * 4, z4);
  }
  grid_barrier(a.flags, ++phase);

  for (int t = 0; t < STEPS; ++t) {
    float* h0cur = (t & 1) ? a.h0b : a.h0a;
    float* h0nxt = (t & 1) ? a.h0a : a.h0b;

    // ---- PH_A: finish step t-1 (h1 + pred) and gh0 GEMM (split-K, 2 halves) ----
    if (t > 0) ew_h1(a, t - 1, bid, tid, red);
    {
      int tile = bid >> 1, p = bid & 1;
      int m0 = (tile >> 4) * BM, n0 = (tile & 15) * BN;
      gemm64x96(h0cur, a.w_hh0, p ? a.ghp1 : a.ghp0,
                p == 0 ? a.b_hh0 : nullptr,   // fold b_hh0 into half 0
                m0, n0, p * 256, p * 256 + 256, tid, As, Ws);
    }
    grid_barrier(a.flags, ++phase);

    // ---- PH_B: layer-0 GRU elementwise -> h0nxt (1 f4 per thread) ----
    {
      size_t fi = (size_t)bid * NTHR + tid;
      int b = (int)(fi >> 7);
      int j0 = (int)(fi & 127) * 4;
      float xv = (t < Tt) ? a.x[(size_t)b * Tt + t] : a.pred[b];
      size_t bg = (size_t)b * G3;
      float4 g0r = ld4(a.ghp0 + bg + j0),        g1r = ld4(a.ghp1 + bg + j0);
      float4 g0z = ld4(a.ghp0 + bg + 512 + j0),  g1z = ld4(a.ghp1 + bg + 512 + j0);
      float4 g0n = ld4(a.ghp0 + bg + 1024 + j0), g1n = ld4(a.ghp1 + bg + 1024 + j0);
      float4 wr = ld4(a.w_ih0 + j0),        br = ld4(a.b_ih0 + j0);
      float4 wz = ld4(a.w_ih0 + 512 + j0),  bz = ld4(a.b_ih0 + 512 + j0);
      float4 wn = ld4(a.w_ih0 + 1024 + j0), bn = ld4(a.b_ih0 + 1024 + j0);
      float4 hold = ld4(h0cur + (size_t)b * Hh + j0);
      float4 hn;
#define COMP(C) hn.C = gru_h(fmaf(xv, wr.C, br.C), fmaf(xv, wz.C, bz.C), \
                             fmaf(xv, wn.C, bn.C), g0r.C + g1r.C,        \
                             g0z.C + g1z.C, g0n.C + g1n.C, hold.C);
      COMP(x) COMP(y) COMP(z) COMP(w)
#undef COMP
      st4(h0nxt + (size_t)b * Hh + j0, hn);
    }
    grid_barrier(a.flags, ++phase);

    // ---- PH_C: gi1 = h0n @ w_ih1^T, gh1 = h1 @ w_hh1^T (512 tiles / 512 blocks) ----
    {
      int g = bid >> 8, r = bid & 255;
      int m0 = (r >> 4) * BM, n0 = (r & 15) * BN;
      if (g == 0)
        gemm64x96(h0nxt, a.w_ih1, a.gi1, a.b_ih1, m0, n0, 0, Hh, tid, As, Ws);
      else
        gemm64x96(a.h1, a.w_hh1, a.gh1, a.b_hh1, m0, n0, 0, Hh, tid, As, Ws);
    }
    grid_barrier(a.flags, ++phase);
  }
  // tail: finish step 254 -> out column 127
  ew_h1(a, STEPS - 1, bid, tid, red);
}

extern "C" void kernel_launch(void* const* d_in, const int* in_sizes, int n_in,
                              void* d_out, int out_size, void* d_ws, size_t ws_size,
                              hipStream_t stream)
{
  Args a;
  a.x     = (const float*)d_in[0];
  // d_in[1] (x_time) and d_in[2] (y_time) are unused by the reference computation
  a.w_ih0 = (const float*)d_in[3];
  a.w_hh0 = (const float*)d_in[4];
  a.b_ih0 = (const float*)d_in[5];
  a.b_hh0 = (const float*)d_in[6];
  a.w_ih1 = (const float*)d_in[7];
  a.w_hh1 = (const float*)d_in[8];
  a.b_ih1 = (const float*)d_in[9];
  a.b_hh1 = (const float*)d_in[10];
  a.w_lin = (const float*)d_in[11];
  a.b_lin = (const float*)d_in[12];
  a.out   = (float*)d_out;

  // flag region at head of workspace (d_ws is poisoned 0xAA before every
  // call -> must re-zero; hipMemsetAsync is graph-capturable)
  a.flags = (unsigned*)d_ws;
  hipMemsetAsync(d_ws, 0, 4096, stream);

  float* w = (float*)((char*)d_ws + 4096);
  size_t off = 0;
  auto take = [&](size_t n) { float* p = w + off; off += n; return p; };
  a.h0a  = take((size_t)Bsz * Hh);
  a.h0b  = take((size_t)Bsz * Hh);
  a.h1   = take((size_t)Bsz * Hh);
  a.ghp0 = take((size_t)Bsz * G3);
  a.ghp1 = take((size_t)Bsz * G3);
  a.gi1  = take((size_t)Bsz * G3);
  a.gh1  = take((size_t)Bsz * G3);
  a.pred = take((size_t)Bsz);
  // total ~31.5 MB of workspace

  regru_kernel<<<dim3(NBLK), dim3(NTHR), 0, stream>>>(a);
}

// Round 13
// 29750.201 us; speedup vs baseline: 3.6404x; 1.5350x over previous
//
#include <hip/hip_runtime.h>

#define DI __device__ __forceinline__

// Problem constants
constexpr int Bsz = 1024;   // batch
constexpr int Hh  = 512;    // hidden
constexpr int Tt  = 128;    // seq len
constexpr int G3  = 1536;   // 3H
constexpr int STEPS = 2 * Tt - 1;  // 255 sequential GRU steps

// Persistent-kernel config
constexpr int NBLK = 512;   // 2 blocks/CU on 256 CUs
constexpr int NTHR = 256;
constexpr int LDT  = 72;    // LDS tile row stride in f16 (144B = 16B-aligned, bank-quad optimal)

typedef _Float16 f16x8 __attribute__((ext_vector_type(8)));
typedef _Float16 f16x4 __attribute__((ext_vector_type(4)));
typedef float    f32x4 __attribute__((ext_vector_type(4)));

struct LdsT {  // 320 rows * 72 f16 * 2B = 46,080 B
  _Float16 Ahi[64 * LDT], Alo[64 * LDT];
  _Float16 Bhi[96 * LDT], Blo[96 * LDT];
};

struct Args {
  const float* x;
  const float* w_ih0; const float* w_hh0; const float* b_ih0; const float* b_hh0;
  const float* w_ih1; const float* w_hh1; const float* b_ih1; const float* b_hh1;
  const float* w_lin; const float* b_lin;
  float* out;
  unsigned* flags;
  float* h0_32; float* h1_32;                  // fp32 states
  _Float16 *h0hi, *h0lo, *h1hi, *h1lo;         // f16 split states for MFMA A
  _Float16 *w0hi, *w0lo, *w1hi, *w1lo, *w2hi, *w2lo;  // split W_hh0 / W_ih1 / W_hh1
  float* gh0; float* gi1; float* gh1;          // gate pre-activations [B,3H] f32
  float* pred;
};

// Distributed flag barrier (validated round 9: 108->45.7ms vs central fetch_add).
DI void grid_barrier(unsigned* flags, unsigned phase) {
  __syncthreads();
  if (threadIdx.x == 0)
    __hip_atomic_store(&flags[blockIdx.x], phase, __ATOMIC_RELEASE, __HIP_MEMORY_SCOPE_AGENT);
  if (threadIdx.x < 64) {
#pragma unroll
    for (int k = 0; k < NBLK / 64; ++k) {
      const unsigned idx = threadIdx.x + 64u * k;
      while (__hip_atomic_load(&flags[idx], __ATOMIC_RELAXED, __HIP_MEMORY_SCOPE_AGENT) < phase)
        __builtin_amdgcn_s_sleep(2);
    }
    __builtin_amdgcn_fence(__ATOMIC_ACQUIRE, "agent");
  }
  __syncthreads();
}

DI float4 ld4(const float* p) { return *reinterpret_cast<const float4*>(p); }
DI void   st4(float* p, float4 v) { *reinterpret_cast<float4*>(p) = v; }

DI float sigmf_(float a) { return 1.0f / (1.0f + expf(-a)); }

DI float gru_h(float gi_r, float gi_z, float gi_n,
               float gh_r, float gh_z, float gh_n, float h) {
  float r = sigmf_(gi_r + gh_r);
  float z = sigmf_(gi_z + gh_z);
  float n = tanhf(gi_n + r * gh_n);
  return (1.0f - z) * n + z * h;
}

// Split x = hi + 2^-11 * lo' (lo' pre-scaled by 2^11 to stay in f16 normal range).
// Return-by-value: clang forbids non-const refs / addresses of vector elements.
struct HL { _Float16 hi, lo; };
DI HL split16(float x) {
  HL r;
  r.hi = (_Float16)x;
  r.lo = (_Float16)((x - (float)r.hi) * 2048.0f);
  return r;
}

// Stage one [ROWS x 64] f16 tile (hi+lo) from global row-major [*,512] into LDS.
template<int ROWS>
DI void stage_tile(_Float16* dsthi, _Float16* dstlo,
                   const _Float16* ghi, const _Float16* glo,
                   int row0, int kc, int tid)
{
  constexpr int UNITS = ROWS * 8;            // 16B units
#pragma unroll
  for (int p = 0; p < (UNITS + NTHR - 1) / NTHR; ++p) {
    int i = tid + NTHR * p;
    if ((UNITS % NTHR == 0) || i < UNITS) {
      int r = i >> 3, u = i & 7;
      size_t go = (size_t)(row0 + r) * Hh + kc + u * 8;
      *(uint4*)&dsthi[r * LDT + u * 8] = *(const uint4*)&ghi[go];
      *(uint4*)&dstlo[r * LDT + u * 8] = *(const uint4*)&glo[go];
    }
  }
}

// Split-f16 MFMA GEMM: C[m0..][n0..] = A(M rows)[.,512] . B^T(BR rows)[.,512] + bias.
// 3-pass compensation: acc1 = AhiBhi; acc2 = AhiBlo' + Alo'Bhi; C = acc1 + 2^-11 acc2.
// mfma_f32_16x16x32_f16 frag: A/B lane&15 = row(of A / of B^T), k = (lane>>4)*8+e;
// D: col = lane&15, row = (lane>>4)*4 + reg  [m89/m91-verified mapping].
template<int TM, int TN, int BR>
DI void gemm_core(LdsT& L,
                  const _Float16* Ahi_g, const _Float16* Alo_g,
                  const _Float16* Bhi_g, const _Float16* Blo_g,
                  float* Cg, const float* bias,
                  int m0, int n0, int wrow, int wcol, int tid)
{
  const int lane = tid & 63;
  const int lr = lane & 15, lq = lane >> 4;
  f32x4 acc1[TM][TN] = {}, acc2[TM][TN] = {};

  for (int kc = 0; kc < 512; kc += 64) {
    stage_tile<64>(L.Ahi, L.Alo, Ahi_g, Alo_g, m0, kc, tid);
    stage_tile<BR>(L.Bhi, L.Blo, Bhi_g, Blo_g, n0, kc, tid);
    __syncthreads();
#pragma unroll
    for (int ks = 0; ks < 2; ++ks) {
      const int ko = ks * 32 + lq * 8;
      f16x8 ah[TM], al[TM], bh[TN], bl[TN];
#pragma unroll
      for (int mt = 0; mt < TM; ++mt) {
        int rr = wrow + mt * 16 + lr;
        ah[mt] = *(const f16x8*)&L.Ahi[rr * LDT + ko];
        al[mt] = *(const f16x8*)&L.Alo[rr * LDT + ko];
      }
#pragma unroll
      for (int nt = 0; nt < TN; ++nt) {
        int rr = wcol + nt * 16 + lr;
        bh[nt] = *(const f16x8*)&L.Bhi[rr * LDT + ko];
        bl[nt] = *(const f16x8*)&L.Blo[rr * LDT + ko];
      }
#pragma unroll
      for (int mt = 0; mt < TM; ++mt)
#pragma unroll
        for (int nt = 0; nt < TN; ++nt) {
          acc1[mt][nt] = __builtin_amdgcn_mfma_f32_16x16x32_f16(ah[mt], bh[nt], acc1[mt][nt], 0, 0, 0);
          acc2[mt][nt] = __builtin_amdgcn_mfma_f32_16x16x32_f16(ah[mt], bl[nt], acc2[mt][nt], 0, 0, 0);
          acc2[mt][nt] = __builtin_amdgcn_mfma_f32_16x16x32_f16(al[mt], bh[nt], acc2[mt][nt], 0, 0, 0);
        }
    }
    __syncthreads();
  }
#pragma unroll
  for (int mt = 0; mt < TM; ++mt) {
    int row = m0 + wrow + mt * 16 + lq * 4;
#pragma unroll
    for (int nt = 0; nt < TN; ++nt) {
      int col = n0 + wcol + nt * 16 + lr;
      float b = bias[col];
#pragma unroll
      for (int i = 0; i < 4; ++i)
        Cg[(size_t)(row + i) * G3 + col] =
            acc1[mt][nt][i] + 0.00048828125f * acc2[mt][nt][i] + b;
    }
  }
}

// layer-1 elementwise + prediction for step tp; each block owns 2 batch rows.
DI void ew_h1(const Args& a, int tp, int bid, int tid, double* red)
{
  const int half = tid >> 7;
  const int r = 2 * bid + half;
  const int j0 = (tid & 127) * 4;
  const size_t rg = (size_t)r * G3;
  float4 gir = ld4(a.gi1 + rg + j0);
  float4 ghr = ld4(a.gh1 + rg + j0);
  float4 giz = ld4(a.gi1 + rg + 512 + j0);
  float4 ghz = ld4(a.gh1 + rg + 512 + j0);
  float4 gin = ld4(a.gi1 + rg + 1024 + j0);
  float4 ghn = ld4(a.gh1 + rg + 1024 + j0);
  float4 hold = ld4(a.h1_32 + (size_t)r * Hh + j0);
  float4 wl = ld4(a.w_lin + j0);
  float4 hn;
  double pd = 0.0;
#define COMP(C) { hn.C = gru_h(gir.C, giz.C, gin.C, ghr.C, ghz.C, ghn.C, hold.C); \
                  pd += (double)hn.C * (double)wl.C; }
  COMP(x) COMP(y) COMP(z) COMP(w)
#undef COMP
  st4(a.h1_32 + (size_t)r * Hh + j0, hn);
  f16x4 hhi, hlo;
  { HL s = split16(hn.x); hhi[0] = s.hi; hlo[0] = s.lo; }
  { HL s = split16(hn.y); hhi[1] = s.hi; hlo[1] = s.lo; }
  { HL s = split16(hn.z); hhi[2] = s.hi; hlo[2] = s.lo; }
  { HL s = split16(hn.w); hhi[3] = s.hi; hlo[3] = s.lo; }
  *(f16x4*)&a.h1hi[(size_t)r * Hh + j0] = hhi;
  *(f16x4*)&a.h1lo[(size_t)r * Hh + j0] = hlo;
#pragma unroll
  for (int s = 32; s; s >>= 1) pd += __shfl_down(pd, s);
  if ((tid & 63) == 0) red[tid >> 6] = pd;
  __syncthreads();
  if ((tid & 127) == 0) {
    int w0 = half * 2;
    float p0 = (float)(red[w0] + red[w0 + 1] + (double)a.b_lin[0]);
    a.pred[r] = p0;
    if (tp >= Tt - 1) a.out[(size_t)r * Tt + (tp - (Tt - 1))] = p0;
  }
}

__global__ __launch_bounds__(NTHR, 2) void regru_kernel(Args a)
{
  const int bid = blockIdx.x;
  const int tid = threadIdx.x;
  const int w   = tid >> 6;

  __shared__ LdsT L;
  __shared__ double red[4];

  unsigned phase = 0;
  const int gtid = bid * NTHR + tid;           // 0..131071

  // ---- prologue: split weights to f16 hi/lo; zero states ----
  {
    constexpr int NW = G3 * Hh;                // 786432 per matrix
    const float* src[3] = { a.w_hh0, a.w_ih1, a.w_hh1 };
    _Float16* dhi[3] = { a.w0hi, a.w1hi, a.w2hi };
    _Float16* dlo[3] = { a.w0lo, a.w1lo, a.w2lo };
    for (int m = 0; m < 3; ++m)
      for (int i = gtid; i < NW; i += NBLK * NTHR) {
        HL s = split16(src[m][i]);
        dhi[m][i] = s.hi; dlo[m][i] = s.lo;
      }
    // zero h states: 4 f32 + 4x4 f16 per thread
    size_t fo = (size_t)gtid * 4;
    st4(a.h0_32 + fo, make_float4(0, 0, 0, 0));
    st4(a.h1_32 + fo, make_float4(0, 0, 0, 0));
    f16x4 z4 = {};
    *(f16x4*)&a.h0hi[fo] = z4; *(f16x4*)&a.h0lo[fo] = z4;
    *(f16x4*)&a.h1hi[fo] = z4; *(f16x4*)&a.h1lo[fo] = z4;
  }
  grid_barrier(a.flags, ++phase);

  for (int t = 0; t < STEPS; ++t) {
    // ---- PH_A: finish step t-1 (h1+pred) and gh0 = h0.Whh0^T (64x48 tiles, full K) ----
    if (t > 0) ew_h1(a, t - 1, bid, tid, red);
    {
      int m0 = (bid >> 5) * 64, n0 = (bid & 31) * 48;
      gemm_core<1, 3, 48>(L, a.h0hi, a.h0lo, a.w0hi, a.w0lo,
                          a.gh0, a.b_hh0, m0, n0, w * 16, 0, tid);
    }
    grid_barrier(a.flags, ++phase);

    // ---- PH_B: layer-0 GRU elementwise -> h0 (f32 + f16 split) ----
    {
      int b = gtid >> 7;
      int j0 = (gtid & 127) * 4;
      float xv = (t < Tt) ? a.x[(size_t)b * Tt + t] : a.pred[b];
      size_t bg = (size_t)b * G3;
      float4 ghr = ld4(a.gh0 + bg + j0);
      float4 ghz = ld4(a.gh0 + bg + 512 + j0);
      float4 ghn = ld4(a.gh0 + bg + 1024 + j0);
      float4 wr = ld4(a.w_ih0 + j0),        br = ld4(a.b_ih0 + j0);
      float4 wz = ld4(a.w_ih0 + 512 + j0),  bz = ld4(a.b_ih0 + 512 + j0);
      float4 wn = ld4(a.w_ih0 + 1024 + j0), bn = ld4(a.b_ih0 + 1024 + j0);
      size_t ho = (size_t)b * Hh + j0;
      float4 hold = ld4(a.h0_32 + ho);
      float4 hn;
#define COMP(C) hn.C = gru_h(fmaf(xv, wr.C, br.C), fmaf(xv, wz.C, bz.C), \
                             fmaf(xv, wn.C, bn.C), ghr.C, ghz.C, ghn.C, hold.C);
      COMP(x) COMP(y) COMP(z) COMP(w)
#undef COMP
      st4(a.h0_32 + ho, hn);
      f16x4 hhi, hlo;
      { HL s = split16(hn.x); hhi[0] = s.hi; hlo[0] = s.lo; }
      { HL s = split16(hn.y); hhi[1] = s.hi; hlo[1] = s.lo; }
      { HL s = split16(hn.z); hhi[2] = s.hi; hlo[2] = s.lo; }
      { HL s = split16(hn.w); hhi[3] = s.hi; hlo[3] = s.lo; }
      *(f16x4*)&a.h0hi[ho] = hhi;
      *(f16x4*)&a.h0lo[ho] = hlo;
    }
    grid_barrier(a.flags, ++phase);

    // ---- PH_C: gi1 = h0.Wih1^T | gh1 = h1.Whh1^T (64x96 tiles, 2x2 waves of 32x48) ----
    {
      int g = bid >> 8, r = bid & 255;
      int m0 = (r >> 4) * 64, n0 = (r & 15) * 96;
      int wrow = (w >> 1) * 32, wcol = (w & 1) * 48;
      if (g == 0)
        gemm_core<2, 3, 96>(L, a.h0hi, a.h0lo, a.w1hi, a.w1lo,
                            a.gi1, a.b_ih1, m0, n0, wrow, wcol, tid);
      else
        gemm_core<2, 3, 96>(L, a.h1hi, a.h1lo, a.w2hi, a.w2lo,
                            a.gh1, a.b_hh1, m0, n0, wrow, wcol, tid);
    }
    grid_barrier(a.flags, ++phase);
  }
  ew_h1(a, STEPS - 1, bid, tid, red);
}

extern "C" void kernel_launch(void* const* d_in, const int* in_sizes, int n_in,
                              void* d_out, int out_size, void* d_ws, size_t ws_size,
                              hipStream_t stream)
{
  Args a;
  a.x     = (const float*)d_in[0];
  a.w_ih0 = (const float*)d_in[3];
  a.w_hh0 = (const float*)d_in[4];
  a.b_ih0 = (const float*)d_in[5];
  a.b_hh0 = (const float*)d_in[6];
  a.w_ih1 = (const float*)d_in[7];
  a.w_hh1 = (const float*)d_in[8];
  a.b_ih1 = (const float*)d_in[9];
  a.b_hh1 = (const float*)d_in[10];
  a.w_lin = (const float*)d_in[11];
  a.b_lin = (const float*)d_in[12];
  a.out   = (float*)d_out;

  a.flags = (unsigned*)d_ws;
  (void)hipMemsetAsync(d_ws, 0, 4096, stream);

  char* w = (char*)d_ws + 4096;
  size_t off = 0;
  auto takeF = [&](size_t n) { float* p = (float*)(w + off); off += n * 4; return p; };
  auto takeH = [&](size_t n) { _Float16* p = (_Float16*)(w + off); off += n * 2; return p; };
  const size_t SH = (size_t)Bsz * Hh;      // 524288
  const size_t SW = (size_t)G3 * Hh;       // 786432
  const size_t SG = (size_t)Bsz * G3;      // 1572864
  a.h0_32 = takeF(SH);  a.h1_32 = takeF(SH);
  a.h0hi = takeH(SH);   a.h0lo = takeH(SH);
  a.h1hi = takeH(SH);   a.h1lo = takeH(SH);
  a.w0hi = takeH(SW);   a.w0lo = takeH(SW);
  a.w1hi = takeH(SW);   a.w1lo = takeH(SW);
  a.w2hi = takeH(SW);   a.w2lo = takeH(SW);
  a.gh0 = takeF(SG);    a.gi1 = takeF(SG);  a.gh1 = takeF(SG);
  a.pred = takeF(Bsz);
  // total ~35 MB of workspace

  regru_kernel<<<dim3(NBLK), dim3(NTHR), 0, stream>>>(a);
}